// Round 3
// baseline (760.992 us; speedup 1.0000x reference)
//
#include <hip/hip_runtime.h>

// Batched Hungarian matcher — exact LSA, scipy-TRAJECTORY-exact.
//
// R8 (resubmit — round 2 bench was an infra failure, no data produced):
// same trajectory-exact JV as R7 (passed, absmax 0, 586us kernel), but
// the per-pop critical path is restructured to have ZERO dependent LDS
// reads:
//   - per-search register preload: for each of my 8 columns j, the matched
//     row r4=row4col[j] and that row's data {u,t0,t1,ch} (all constant
//     within a search; they change only between searches).
//   - meta = (j<<12)|((r4+1)<<2)|ch: integer order == j order, so the
//     (value, meta) compare implements scipy's exact lowest-j tie-break.
//   - wave butterfly on (bv, meta); winning column's row data pulled from
//     its owner lane via a constant-index cndmask tree + one shfl each
//     (no runtime-indexed arrays -> no scratch).
//   - cross-wave: leader writes {bv,meta,u,t0,t1}; after the barrier every
//     8-lane group reads all 8 wave candidates (same addr -> LDS broadcast)
//     and 3-step shfl-reduces them, so ALL lanes hold the global result —
//     no serial 8-way compare, no row4col/rowdata LDS reads per pop.
// Evaluation order ((minv + cf) - u) - v, strictly-better updates, and the
// pop sequence are bit-identical to scipy's _lsa.

#define Bb 32
#define Nn 4096
#define Mm 128
#define Tt 512
#define Kk (Nn / Tt)   // 8 columns per thread
#define TSH 9          // log2(Tt)
#define NW (Tt / 64)   // 8 waves
#define RECMAX 160

__global__ __launch_bounds__(Tt, 1)
void hungarian_kernel(const float* __restrict__ predict_scores,
                      const float* __restrict__ predict_points,
                      const int*   __restrict__ scores,
                      const float* __restrict__ points,
                      int* __restrict__ out)
{
    __shared__ double vvl[Nn];           // column duals v (exact f64)
    __shared__ short  path_lds[Nn];      // predecessor row per column
    __shared__ short  row4col[Nn];       // matched row per column (-1 free)
    __shared__ double uu[Mm];            // row duals u
    __shared__ short  col4row[Mm];       // matched column per row (-1 free)
    __shared__ double srow_val[Mm];      // shortest[col4row[i]] at scan time
    __shared__ unsigned char SRr[Mm];    // scanned-row flags
    __shared__ float  tx0[Mm], tx1[Mm];
    __shared__ int    tch[Mm];
    __shared__ short  scol[RECMAX];      // popped (SC) columns this search
    __shared__ double sval[RECMAX];      // their pop values
    __shared__ int    nsc_lds;
    __shared__ double wv_[2][NW];        // per-wave candidate: value
    __shared__ int    wm_[2][NW];        //   meta (j<<12 | (r4+1)<<2 | ch)
    __shared__ double wu_[2][NW];        //   u[r4]
    __shared__ float  wt0_[2][NW];       //   t0[r4]
    __shared__ float  wt1_[2][NW];       //   t1[r4]

    const int b    = blockIdx.x;
    const int tid  = threadIdx.x;
    const int lane = tid & 63;
    const int wid  = tid >> 6;
    const double INFD = __builtin_inf();

    // ---- per-column data -> registers ----
    float negp0[Kk], negp1[Kk], qx0[Kk], qx1[Kk];
    const float* ps = predict_scores + (size_t)b * Nn * 2;
    const float* pp = predict_points + (size_t)b * Nn * 2;
    #pragma unroll
    for (int k = 0; k < Kk; ++k) {
        int j = tid + (k << TSH);
        float2 sc = ((const float2*)ps)[j];
        float mx = fmaxf(sc.x, sc.y);
        float e0 = expf(sc.x - mx), e1 = expf(sc.y - mx);
        float sm = e0 + e1;
        float n0 = -(e0 / sm), n1 = -(e1 / sm);
        float2 qp = ((const float2*)pp)[j];
        negp0[k] = n0; negp1[k] = n1;
        qx0[k] = qp.x; qx1[k] = qp.y;
        vvl[j] = 0.0;
        row4col[j] = -1;
    }
    if (tid < Mm) {
        col4row[tid] = -1;
        SRr[tid] = 0;
        uu[tid] = 0.0;                    // scipy: duals start at zero
        tx0[tid] = points[(size_t)b * Mm * 2 + 2 * tid];
        tx1[tid] = points[(size_t)b * Mm * 2 + 2 * tid + 1];
        tch[tid] = scores[(size_t)b * Mm + tid];
    }
    __syncthreads();

    // ---- JV: one shortest-augmenting-path search per row, scipy order ----
    for (int cur_row = 0; cur_row < Mm; ++cur_row) {
        // per-search register preload (all constant within the search)
        double shr[Kk], vreg[Kk], upre[Kk];
        float  t0pre[Kk], t1pre[Kk];
        int    premeta[Kk];
        #pragma unroll
        for (int k = 0; k < Kk; ++k) {
            int j = tid + (k << TSH);
            shr[k]  = INFD;
            vreg[k] = vvl[j];
            int r4  = row4col[j];
            int rr  = (r4 < 0) ? 0 : r4;
            upre[k]  = uu[rr];
            t0pre[k] = tx0[rr];
            t1pre[k] = tx1[rr];
            int chb  = (tch[rr] == 1) ? 1 : 0;
            premeta[k] = (j << 12) | ((r4 + 1) << 2) | chb;
        }
        unsigned scmask = 0;
        int    i = cur_row;
        double minv = 0.0;
        int    sink = -1, par = 0, nsc = 0;
        // scan-row data (registers; refreshed from the reduce payload)
        double ui  = uu[cur_row];
        float  it0 = tx0[cur_row], it1 = tx1[cur_row];
        int    ich = (tch[cur_row] == 1) ? 1 : 0;

        for (;;) {
            // ---- relax row i over all 4096 columns (exact f64, scipy order) ----
            double bv = INFD; int bm = 0x7FFFFFFF;
            #pragma unroll
            for (int k = 0; k < Kk; ++k) {
                float pres = ich ? negp1[k] : negp0[k];
                float cf = pres + (fabsf(qx0[k] - it0) + fabsf(qx1[k] - it1));
                double r = ((minv + (double)cf) - ui) - vreg[k];
                bool sc = (scmask >> k) & 1u;
                if (!sc && r < shr[k]) { shr[k] = r; path_lds[tid + (k << TSH)] = (short)i; }
                double sj = sc ? INFD : shr[k];
                if (sj < bv) { bv = sj; bm = premeta[k]; }  // k asc => lowest j on tie
            }
            // ---- wave butterfly: all lanes get wave-min (bv, bm) ----
            #pragma unroll
            for (int off = 32; off > 0; off >>= 1) {
                double ov = __shfl_xor(bv, off);
                int    om = __shfl_xor(bm, off);
                if (ov < bv || (ov == bv && om < bm)) { bv = ov; bm = om; }
            }
            // ---- pull winning column's row data from its owner lane ----
            int kb = (bm >> 21) & 7;        // k index of wave-best column
            int ol = (bm >> 12) & 63;       // owner lane of wave-best column
            double ua0 = (kb & 1) ? upre[1] : upre[0];
            double ua1 = (kb & 1) ? upre[3] : upre[2];
            double ua2 = (kb & 1) ? upre[5] : upre[4];
            double ua3 = (kb & 1) ? upre[7] : upre[6];
            double ub0 = (kb & 2) ? ua1 : ua0;
            double ub1 = (kb & 2) ? ua3 : ua2;
            double uX  = (kb & 4) ? ub1 : ub0;
            float  fa0 = (kb & 1) ? t0pre[1] : t0pre[0];
            float  fa1 = (kb & 1) ? t0pre[3] : t0pre[2];
            float  fa2 = (kb & 1) ? t0pre[5] : t0pre[4];
            float  fa3 = (kb & 1) ? t0pre[7] : t0pre[6];
            float  fb0 = (kb & 2) ? fa1 : fa0;
            float  fb1 = (kb & 2) ? fa3 : fa2;
            float  f0X = (kb & 4) ? fb1 : fb0;
            float  ga0 = (kb & 1) ? t1pre[1] : t1pre[0];
            float  ga1 = (kb & 1) ? t1pre[3] : t1pre[2];
            float  ga2 = (kb & 1) ? t1pre[5] : t1pre[4];
            float  ga3 = (kb & 1) ? t1pre[7] : t1pre[6];
            float  gb0 = (kb & 2) ? ga1 : ga0;
            float  gb1 = (kb & 2) ? ga3 : ga2;
            float  g1X = (kb & 4) ? gb1 : gb0;
            double su = __shfl(uX, ol);
            float  s0 = __shfl(f0X, ol);
            float  s1 = __shfl(g1X, ol);
            if (lane == 0) {
                wv_[par][wid] = bv;  wm_[par][wid] = bm;
                wu_[par][wid] = su;  wt0_[par][wid] = s0;  wt1_[par][wid] = s1;
            }
            __syncthreads();
            // ---- cross-wave mini-reduce: every 8-lane group reduces the 8
            //      wave candidates -> ALL lanes hold the global min ----
            int l8 = lane & 7;
            double mv = wv_[par][l8];  int mm = wm_[par][l8];
            double mu = wu_[par][l8];
            float  m0 = wt0_[par][l8], m1 = wt1_[par][l8];
            #pragma unroll
            for (int off = 1; off < 8; off <<= 1) {
                double ov = __shfl_xor(mv, off);
                int    om = __shfl_xor(mm, off);
                double ou = __shfl_xor(mu, off);
                float  o0 = __shfl_xor(m0, off);
                float  o1 = __shfl_xor(m1, off);
                if (ov < mv || (ov == mv && om < mm)) {
                    mv = ov; mm = om; mu = ou; m0 = o0; m1 = o1;
                }
            }
            par ^= 1;
            minv = mv;
            int bj = mm >> 12;
            int r4 = ((mm >> 2) & 0xFF) - 1;
            if ((bj & (Tt - 1)) == tid) scmask |= (1u << (bj >> TSH));
            if (r4 < 0) {
                if (tid == 0) nsc_lds = nsc;
                sink = bj;
                break;                             // uniform exit
            }
            if (tid == 0) {
                SRr[r4] = 1; srow_val[r4] = mv;
                scol[nsc] = (short)bj; sval[nsc] = mv; ++nsc;
            }
            i = r4; ui = mu; it0 = m0; it1 = m1; ich = mm & 1;
        }
        __syncthreads();                           // publish nsc/SRr/records/path

        // ---- dual updates (scipy-exact op order) + augment ----
        const double minvF = minv;
        if (tid < Mm) {
            if (tid == cur_row)   uu[tid] += minvF;
            else if (SRr[tid])    uu[tid] += minvF - srow_val[tid];
            SRr[tid] = 0;
        }
        int S = nsc_lds;
        if (tid < S) {
            int jc = scol[tid];
            vvl[jc] -= (minvF - sval[tid]);
        }
        if (tid == 0) {
            int j = sink;
            for (;;) {
                int i2 = path_lds[j];
                row4col[j] = (short)i2;
                int nxt = col4row[i2];
                col4row[i2] = (short)j;
                j = nxt;
                if (i2 == cur_row) break;
            }
        }
        __syncthreads();
    }

    // ---- emit (batch, src sorted ascending, tgt) ----
    if (tid < Mm) {
        int myj = col4row[tid];
        int rank = 0;
        #pragma unroll 4
        for (int t = 0; t < Mm; ++t) rank += (col4row[t] < myj) ? 1 : 0;
        out[b * Mm + tid] = b;                  // batch_idx
        out[Bb * Mm + b * Mm + rank] = myj;     // src_idx (sorted)
        out[2 * Bb * Mm + b * Mm + rank] = tid; // tgt_idx
    }
}

extern "C" void kernel_launch(void* const* d_in, const int* in_sizes, int n_in,
                              void* d_out, int out_size, void* d_ws, size_t ws_size,
                              hipStream_t stream) {
    (void)in_sizes; (void)n_in; (void)d_ws; (void)ws_size; (void)out_size;
    const float* predict_scores = (const float*)d_in[0];
    const float* predict_points = (const float*)d_in[1];
    const int*   scores         = (const int*)d_in[2];
    const float* points         = (const float*)d_in[3];
    int* out = (int*)d_out;
    hipLaunchKernelGGL(hungarian_kernel, dim3(Bb), dim3(Tt), 0, stream,
                       predict_scores, predict_points, scores, points, out);
}

// Round 4
// 571.036 us; speedup vs baseline: 1.3327x; 1.3327x over previous
//
#include <hip/hip_runtime.h>

// Batched Hungarian matcher — exact LSA, scipy-TRAJECTORY-exact.
//
// R9: R7 base (586us, passed) + surgical critical-path cuts. R8's lesson:
// random-index LDS preload (30K bank conflicts) + payload-heavy shfl
// reduces (f64 = 2x b32 shfls, x2 waves/SIMD) cost more throughput than
// the latency they saved (714us). R9 keeps only the cheap wins:
//   - meta = (j<<8)|(r4+1): carrying the matched row INSIDE the reduce is
//     free (int cndmask, same cost as carrying j). Integer order == j
//     order => scipy's lowest-j tie-break preserved. Eliminates the
//     dependent row4col[bestj] LDS read per pop (-120cy).
//   - r4pre[k] = row4col[tid + k*512] preloaded per search: LINEAR
//     stride-512 short reads, conflict-free (unlike R8's random gather).
//   - row data {u,t0,t1,ch} for 128 rows wave-distributed: lane l caches
//     rows l and l+64 in registers (uu refreshed per search; tx/tch
//     immutable). Next row's data via 1 cndmask + 1 __shfl per value
//     (~10 insts) instead of a 120cy dependent LDS round trip.
//   - cross-wave tail: lane&7 reads ONE candidate (2 LDS broadcast reads,
//     not 16) + 3-step shfl_xor mini-reduce on (f64,int) — all 64 lanes
//     get the global min; lighter than the serial-8 compare chain.
//   - ich (presence-class of scan row) is wave-uniform: readfirstlane +
//     uniform branch hoists the per-k pres cndmask out of the relax loop.
// Evaluation order ((minv + cf) - u) - v, strictly-better updates, pop
// sequence and tie-breaks bit-identical to scipy's _lsa.

#define Bb 32
#define Nn 4096
#define Mm 128
#define Tt 512
#define Kk (Nn / Tt)   // 8 columns per thread
#define TSH 9          // log2(Tt)
#define NW (Tt / 64)   // 8 waves
#define RECMAX 160

__global__ __launch_bounds__(Tt, 1)
void hungarian_kernel(const float* __restrict__ predict_scores,
                      const float* __restrict__ predict_points,
                      const int*   __restrict__ scores,
                      const float* __restrict__ points,
                      int* __restrict__ out)
{
    __shared__ double vvl[Nn];           // column duals v (exact f64)
    __shared__ short  path_lds[Nn];      // predecessor row per column
    __shared__ short  row4col[Nn];       // matched row per column (-1 free)
    __shared__ double uu[Mm];            // row duals u
    __shared__ short  col4row[Mm];       // matched column per row (-1 free)
    __shared__ double srow_val[Mm];      // shortest[col4row[i]] at scan time
    __shared__ unsigned char SRr[Mm];    // scanned-row flags
    __shared__ float  tx0[Mm], tx1[Mm];
    __shared__ int    tch[Mm];
    __shared__ short  scol[RECMAX];      // popped (SC) columns this search
    __shared__ double sval[RECMAX];      // their pop values
    __shared__ int    nsc_lds;
    __shared__ double wv_[2][NW];        // per-wave candidate: value
    __shared__ int    wm_[2][NW];        //   meta (j<<8 | (r4+1))

    const int b    = blockIdx.x;
    const int tid  = threadIdx.x;
    const int lane = tid & 63;
    const int wid  = tid >> 6;
    const double INFD = __builtin_inf();

    // ---- per-column data -> registers ----
    float negp0[Kk], negp1[Kk], qx0[Kk], qx1[Kk];
    const float* ps = predict_scores + (size_t)b * Nn * 2;
    const float* pp = predict_points + (size_t)b * Nn * 2;
    #pragma unroll
    for (int k = 0; k < Kk; ++k) {
        int j = tid + (k << TSH);
        float2 sc = ((const float2*)ps)[j];
        float mx = fmaxf(sc.x, sc.y);
        float e0 = expf(sc.x - mx), e1 = expf(sc.y - mx);
        float sm = e0 + e1;
        float n0 = -(e0 / sm), n1 = -(e1 / sm);
        float2 qp = ((const float2*)pp)[j];
        negp0[k] = n0; negp1[k] = n1;
        qx0[k] = qp.x; qx1[k] = qp.y;
        vvl[j] = 0.0;
        row4col[j] = -1;
    }
    if (tid < Mm) {
        col4row[tid] = -1;
        SRr[tid] = 0;
        uu[tid] = 0.0;                    // scipy: duals start at zero
        tx0[tid] = points[(size_t)b * Mm * 2 + 2 * tid];
        tx1[tid] = points[(size_t)b * Mm * 2 + 2 * tid + 1];
        tch[tid] = scores[(size_t)b * Mm + tid];
    }
    __syncthreads();

    // ---- wave-distributed row-data cache: lane l holds rows l, l+64 ----
    const float t0_c0 = tx0[lane], t0_c1 = tx0[lane + 64];
    const float t1_c0 = tx1[lane], t1_c1 = tx1[lane + 64];
    const int   ch_c0 = tch[lane], ch_c1 = tch[lane + 64];

    // relax body: PRES = per-class presence array (uniform per pop)
    #define RELAX(PRES)                                                        \
        _Pragma("unroll")                                                      \
        for (int k = 0; k < Kk; ++k) {                                         \
            float cf = PRES[k] + (fabsf(qx0[k] - it0) + fabsf(qx1[k] - it1));  \
            double r = ((minv + (double)cf) - ui) - vreg[k];                   \
            bool scb = (scmask >> k) & 1u;                                     \
            if (!scb && r < shr[k]) {                                          \
                shr[k] = r; path_lds[tid + (k << TSH)] = (short)i;             \
            }                                                                  \
            double sj = scb ? INFD : shr[k];                                   \
            if (sj < bv) { bv = sj; bm = premeta[k]; }                         \
        }

    // ---- JV: one shortest-augmenting-path search per row, scipy order ----
    for (int cur_row = 0; cur_row < Mm; ++cur_row) {
        // per-search register preload (constant within the search)
        double shr[Kk], vreg[Kk];
        int    premeta[Kk];
        double u_c0 = uu[lane], u_c1 = uu[lane + 64];   // refreshed: u changes between searches
        #pragma unroll
        for (int k = 0; k < Kk; ++k) {
            int j = tid + (k << TSH);
            shr[k]  = INFD;
            vreg[k] = vvl[j];
            premeta[k] = (j << 8) | ((int)row4col[j] + 1);  // linear, conflict-free
        }
        unsigned scmask = 0;
        int    i = cur_row;
        double minv = 0.0;
        int    sink = -1, par = 0, nsc = 0;
        double ui  = uu[cur_row];
        float  it0 = tx0[cur_row], it1 = tx1[cur_row];
        int    ich = __builtin_amdgcn_readfirstlane((tch[cur_row] == 1) ? 1 : 0);

        for (;;) {
            // ---- relax row i over all 4096 columns (exact f64, scipy order) ----
            double bv = INFD; int bm = 0x7FFFFFFF;
            if (ich) { RELAX(negp1) } else { RELAX(negp0) }

            // ---- wave butterfly: all lanes get wave-min (bv, bm) ----
            #pragma unroll
            for (int off = 32; off > 0; off >>= 1) {
                double ov = __shfl_xor(bv, off);
                int    om = __shfl_xor(bm, off);
                if (ov < bv || (ov == bv && om < bm)) { bv = ov; bm = om; }
            }
            if (lane == 0) { wv_[par][wid] = bv; wm_[par][wid] = bm; }
            __syncthreads();

            // ---- cross-wave: lane&7 reads ONE candidate, 3-step mini-reduce
            //      -> all 64 lanes hold the global (mv, mm) ----
            int l8 = lane & 7;
            double mv = wv_[par][l8];
            int    mm = wm_[par][l8];
            #pragma unroll
            for (int off = 1; off < 8; off <<= 1) {
                double ov = __shfl_xor(mv, off);
                int    om = __shfl_xor(mm, off);
                if (ov < mv || (ov == mv && om < mm)) { mv = ov; mm = om; }
            }
            par ^= 1;
            minv = mv;
            int bj = __builtin_amdgcn_readfirstlane(mm >> 8);
            int r4 = __builtin_amdgcn_readfirstlane((mm & 0xFF) - 1);
            if ((bj & (Tt - 1)) == tid) scmask |= (1u << (bj >> TSH));
            if (r4 < 0) {
                if (tid == 0) nsc_lds = nsc;
                sink = bj;
                break;                             // uniform exit
            }
            if (tid == 0) {
                SRr[r4] = 1; srow_val[r4] = mv;
                scol[nsc] = (short)bj; sval[nsc] = mv; ++nsc;
            }
            // ---- next scan row's data via wave-distributed shfl (no LDS) ----
            i = r4;
            {
                int hi = r4 >> 6, lx = r4 & 63;
                double us = hi ? u_c1 : u_c0;
                float  f0 = hi ? t0_c1 : t0_c0;
                float  f1 = hi ? t1_c1 : t1_c0;
                int    cs = hi ? ch_c1 : ch_c0;
                ui  = __shfl(us, lx);
                it0 = __shfl(f0, lx);
                it1 = __shfl(f1, lx);
                ich = __builtin_amdgcn_readfirstlane(__shfl(cs, lx) == 1 ? 1 : 0);
            }
        }
        __syncthreads();                           // publish nsc/SRr/records/path

        // ---- dual updates (scipy-exact op order) + augment ----
        const double minvF = minv;
        if (tid < Mm) {
            if (tid == cur_row)   uu[tid] += minvF;
            else if (SRr[tid])    uu[tid] += minvF - srow_val[tid];
            SRr[tid] = 0;
        }
        int S = nsc_lds;
        if (tid < S) {
            int jc = scol[tid];
            vvl[jc] -= (minvF - sval[tid]);
        }
        if (tid == 0) {
            int j = sink;
            for (;;) {
                int i2 = path_lds[j];
                row4col[j] = (short)i2;
                int nxt = col4row[i2];
                col4row[i2] = (short)j;
                j = nxt;
                if (i2 == cur_row) break;
            }
        }
        __syncthreads();
    }
    #undef RELAX

    // ---- emit (batch, src sorted ascending, tgt) ----
    if (tid < Mm) {
        int myj = col4row[tid];
        int rank = 0;
        #pragma unroll 4
        for (int t = 0; t < Mm; ++t) rank += (col4row[t] < myj) ? 1 : 0;
        out[b * Mm + tid] = b;                  // batch_idx
        out[Bb * Mm + b * Mm + rank] = myj;     // src_idx (sorted)
        out[2 * Bb * Mm + b * Mm + rank] = tid; // tgt_idx
    }
}

extern "C" void kernel_launch(void* const* d_in, const int* in_sizes, int n_in,
                              void* d_out, int out_size, void* d_ws, size_t ws_size,
                              hipStream_t stream) {
    (void)in_sizes; (void)n_in; (void)d_ws; (void)ws_size; (void)out_size;
    const float* predict_scores = (const float*)d_in[0];
    const float* predict_points = (const float*)d_in[1];
    const int*   scores         = (const int*)d_in[2];
    const float* points         = (const float*)d_in[3];
    int* out = (int*)d_out;
    hipLaunchKernelGGL(hungarian_kernel, dim3(Bb), dim3(Tt), 0, stream,
                       predict_scores, predict_points, scores, points, out);
}